// Round 12
// baseline (120.509 us; speedup 1.0000x reference)
//
#include <hip/hip_runtime.h>
#include <cstdint>

typedef __bf16 bf16_t;
typedef __bf16 bf16x8 __attribute__((ext_vector_type(8)));
typedef float  f32x4  __attribute__((ext_vector_type(4)));

// Workspace: only the prepacked weights now (Xp eliminated — fused into k_conv).
#define WPERM_ELEMS (256UL*9*128)        // 294912
#define WS_NEEDED  (WPERM_ELEMS*2)

// ------- weight prepack: OIHW f32 -> Wpk[t][kc][o][e] register-fragment image -------
// i = t*8192 + kc*2048 + o*8 + e ; value = wt[o][c = ci*32 + kc*8 + e][tap rs],
// with ci = t&3, rs = t>>2. A-frag for lane(fr,fg): o = wv*64+mi*16+fr, kc = fg.
__global__ void k_wperm(const float* __restrict__ wt, bf16_t* __restrict__ Wp) {
  int i = blockIdx.x * 256 + threadIdx.x;
  if (i >= 294912) return;
  int e  = i & 7;
  int o  = (i >> 3) & 255;
  int kc = (i >> 11) & 3;
  int t  = i >> 13;
  int ci = t & 3, rs = t >> 2;
  int c  = ci * 32 + kc * 8 + e;
  Wp[i] = (bf16_t)wt[o * 1152 + c * 9 + rs];
}

// ---------------- naive fp32 fallback (only if ws too small) ----------------
__global__ void k_naive(const float* __restrict__ x, const float* __restrict__ wt,
                        const float* __restrict__ bs, float* __restrict__ out) {
  int idx = blockIdx.x * 256 + threadIdx.x;
  if (idx >= 25690112) return;
  int w = idx % 56; int tmp = idx / 56;
  int h = tmp % 56; tmp /= 56;
  int k = tmp % 256; int n = tmp / 256;
  float acc = bs[k];
  for (int c = 0; c < 128; ++c)
    for (int r = 0; r < 3; ++r) {
      int hy = h + r - 1; if ((unsigned)hy >= 56u) continue;
      for (int s = 0; s < 3; ++s) {
        int wx = w + s - 1; if ((unsigned)wx >= 56u) continue;
        acc += x[((size_t)(n * 128 + c) * 56 + hy) * 56 + wx] *
               wt[((size_t)(k * 128 + c) * 3 + r) * 3 + s];
      }
    }
  out[idx] = acc;
}

// ---------------- main conv: fused NCHW->strip staging + r9 K-loop ----------------
// Block = 4 waves (256 thr); wave owns 64 out-ch x 112 px (2 output rows).
// Staging (fused, replaces the old k_xform prepass): 8 slabs of 16 channels;
//   coalesced 224B f32 row-segment loads -> tmp[c16][r4][58] -> bf16 convert/pack ->
//   swizzled ds_write_b128 into strip (identical layout/swizzle to r9).
// B: 4-row strip [pix 4*58][chunk16][8ch] bf16, chunk-XOR swizzle cl^=(wp&7).
// A: reg-resident, distance-2 prefetch from L2-resident Wpk.
// K-loop: NO barriers, bfr distance-1 dbuf, setprio around MFMA cluster (r9 verbatim).
__global__ __launch_bounds__(256, 2) void k_conv(const float* __restrict__ x,
                                                 const bf16_t* __restrict__ Wpk,
                                                 const float* __restrict__ bias,
                                                 float* __restrict__ out) {
  __shared__ bf16_t strip[3712 * 8];      // 59392 B: [pix 4*58][chunk16][8ch]
  __shared__ float  tmp[16 * 4 * 58];     // 14848 B slab transpose buffer
  const int tid = threadIdx.x, lane = tid & 63, wv = tid >> 6;   // wv 0..3
  const int sid = (int)blockIdx.x;        // 0..895
  const int n   = sid / 28;
  const int h0  = (sid - n * 28) * 2;     // padded strip rows h0..h0+3

  const int fr = lane & 15, fg = lane >> 4;

  // ---- A fragment prefetch FIRST (in flight under staging) ----
  const bf16_t* wsrc = Wpk + fg * 2048 + ((wv << 6) + fr) * 8;  // + t*8192 + mi*128
  bf16x8 areg[2][4];
#pragma unroll
  for (int mi = 0; mi < 4; ++mi) {
    areg[0][mi] = *(const bf16x8*)(wsrc + mi * 128);            // t=0
    areg[1][mi] = *(const bf16x8*)(wsrc + 8192 + mi * 128);     // t=1
  }

  // ---- fused staging: x (NCHW f32) -> strip (swizzled NHWC bf16) ----
  const float* xs = x + (size_t)n * 401408;     // + c*3136 + h*56 + w
  const int cw = tid >> 6, wl = tid & 63;       // load mapping
  for (int s = 0; s < 8; ++s) {                 // 16-channel slabs
#pragma unroll
    for (int k = 0; k < 16; ++k) {              // 64 (c,r) segments, 4 per round
      int cr = k * 4 + cw;
      int c = cr >> 2, r = cr & 3;
      int h_in = h0 + r - 1;                    // input row for padded row r
      float v = 0.f;
      if (((unsigned)h_in < 56u) & (wl < 56))
        v = xs[(size_t)(s * 16 + c) * 3136 + h_in * 56 + wl];
      if (wl < 56) tmp[(c * 4 + r) * 58 + wl] = v;
    }
    __syncthreads();
#pragma unroll
    for (int rd = 0; rd < 2; ++rd) {            // 464 strip slots (2 chunks x 232 px)
      int slot = rd * 256 + tid;
      if (slot < 464) {
        int half = slot & 1, pix = slot >> 1;
        int hp = pix / 58, wp = pix - hp * 58;
        int cl = s * 2 + half;                  // logical chunk
        int cp = cl ^ (wp & 7);                 // physical slot (involution)
        unsigned pk0 = 0, pk1 = 0, pk2 = 0, pk3 = 0;
        if (wp >= 1 && wp <= 56) {
          const float* tb = &tmp[(half * 8) * 4 * 58 + hp * 58 + (wp - 1)];
          unsigned u[8];
#pragma unroll
          for (int e = 0; e < 8; ++e)
            u[e] = (unsigned)__builtin_bit_cast(unsigned short, (bf16_t)tb[e * 4 * 58]);
          pk0 = u[0] | (u[1] << 16); pk1 = u[2] | (u[3] << 16);
          pk2 = u[4] | (u[5] << 16); pk3 = u[6] | (u[7] << 16);
        }
        uint4 uq; uq.x = pk0; uq.y = pk1; uq.z = pk2; uq.w = pk3;
        *(uint4*)&strip[((size_t)pix * 16 + cp) * 8] = uq;
      }
    }
    __syncthreads();                            // protect tmp reuse next slab
  }
  // strip fully resident; waves free-run from here (no more barriers)

  // ---- per-lane geometry ----
  int pixoff[7];
#pragma unroll
  for (int ni = 0; ni < 7; ++ni) {
    int pq = ni * 16 + fr;                // tile pixel 0..111
    int oh = (pq >= 56) ? 1 : 0;
    pixoff[ni] = (pq + 2 * oh) * 128;     // strip element offset of pixel
  }

  // B-fragment base for step t (compile-time r,s,ci under full unroll):
#define BBASE(t) ((((((t) >> 2) / 3) * 58 + ((t) >> 2) % 3) * 16 +                 \
                   ((((t) & 3) * 4 + fg) ^ ((fr + ((t) >> 2) % 3) & 7))) * 8)

  f32x4 acc[4][7] = {};
  bf16x8 bcur[7], bnxt[7];
#pragma unroll
  for (int ni = 0; ni < 7; ++ni)
    bcur[ni] = *(const bf16x8*)&strip[pixoff[ni] + BBASE(0)];

#pragma unroll
  for (int t = 0; t < 36; ++t) {
    const int pb = t & 1;                 // static under full unroll
    if (t + 1 < 36) {
      const int nb = BBASE(t + 1);
#pragma unroll
      for (int ni = 0; ni < 7; ++ni)
        bnxt[ni] = *(const bf16x8*)&strip[pixoff[ni] + nb];
    }
    __builtin_amdgcn_s_setprio(1);
#pragma unroll
    for (int mi = 0; mi < 4; ++mi)
#pragma unroll
      for (int ni = 0; ni < 7; ++ni)
        acc[mi][ni] = __builtin_amdgcn_mfma_f32_16x16x32_bf16(areg[pb][mi], bcur[ni], acc[mi][ni], 0, 0, 0);
    __builtin_amdgcn_s_setprio(0);
    if (t + 2 < 36) {                     // distance-2 A prefetch into freed slots
#pragma unroll
      for (int mi = 0; mi < 4; ++mi)
        areg[pb][mi] = *(const bf16x8*)(wsrc + (size_t)(t + 2) * 8192 + mi * 128);
    }
#pragma unroll
    for (int ni = 0; ni < 7; ++ni)        // SSA-renamed under unroll
      bcur[ni] = bnxt[ni];
  }
#undef BBASE

  // ---- epilogue: D reg j -> k = wv*64 + mi*16 + fg*4 + j, col = pixel fr ----
  const int mbase = wv * 64;
  float bv[4][4];
#pragma unroll
  for (int mi = 0; mi < 4; ++mi)
#pragma unroll
    for (int j = 0; j < 4; ++j)
      bv[mi][j] = bias[mbase + mi * 16 + fg * 4 + j];

#pragma unroll
  for (int ni = 0; ni < 7; ++ni) {
    int pq = ni * 16 + fr;
    int oh = (pq >= 56) ? 1 : 0;
    int ow = pq - oh * 56;
    int h = h0 + oh;
    float* ob = out + (size_t)n * 802816 + h * 56 + ow;
#pragma unroll
    for (int mi = 0; mi < 4; ++mi) {
      int kb = mbase + mi * 16 + fg * 4;
#pragma unroll
      for (int j = 0; j < 4; ++j)
        ob[(size_t)(kb + j) * 3136] = acc[mi][ni][j] + bv[mi][j];
    }
  }
}

extern "C" void kernel_launch(void* const* d_in, const int* in_sizes, int n_in,
                              void* d_out, int out_size, void* d_ws, size_t ws_size,
                              hipStream_t stream) {
  const float* x  = (const float*)d_in[0];
  const float* wt = (const float*)d_in[1];
  const float* bs = (const float*)d_in[2];
  float* out = (float*)d_out;

  if (ws_size < WS_NEEDED) {     // safety net: direct fp32 conv
    k_naive<<<(25690112 + 255) / 256, 256, 0, stream>>>(x, wt, bs, out);
    return;
  }

  bf16_t* Wpk = (bf16_t*)d_ws;

  k_wperm<<<1152, 256, 0, stream>>>(wt, Wpk);               // 294912 / 256
  k_conv <<<896, 256, 0, stream>>>(x, Wpk, bs, out);        // 32 img * 28 strips
}